// Round 7
// baseline (261.018 us; speedup 1.0000x reference)
//
#include <hip/hip_runtime.h>

// Integrator: y = cumsum(x, axis=-1) over (8,4,1048576) fp32.
// Two-kernel reduce-then-scan (measured-optimal structure; ledger: lookback
// +955us, cooperative grid.sync +120us, nt-stores +130us (2.5x WRITE_SIZE),
// 8192-float tiles +5us). This round: 4 tiles/block (2048 blocks) for 4x
// deeper per-thread load ILP in A, amortized predecessor-reduce + register
// prefetch chain in B. part[] layout and values bit-identical to the 8192-
// block version.
// HBM floor: 134 MB read + 134 MB write; B's x re-read is L3-resident.

constexpr int ROWS           = 32;        // B*C = 8*4
constexpr int T_LEN          = 1048576;
constexpr int THREADS        = 256;
constexpr int PER_THREAD     = 16;        // contiguous floats per thread per tile
constexpr int TILE           = THREADS * PER_THREAD;    // 4096 floats
constexpr int TILES_PER_ROW  = T_LEN / TILE;            // 256
constexpr int TPG            = 4;                       // tiles per block
constexpr int GROUPS_PER_ROW = TILES_PER_ROW / TPG;     // 64
constexpr int TOTAL_GROUPS   = ROWS * GROUPS_PER_ROW;   // 2048

// ---------------- A: per-tile sums, 4 tiles/block ----------------
__global__ __launch_bounds__(THREADS) void integ_reduce(
    const float* __restrict__ x, float* __restrict__ part) {
  const int blk  = blockIdx.x;
  const int t    = threadIdx.x;
  const int lane = t & 63;
  const int wid  = t >> 6;

  const float4* p = (const float4*)(x + (size_t)blk * (TILE * TPG));

  // 16 independent loads in flight (4 per tile x 4 tiles)
  float4 q[TPG][4];
#pragma unroll
  for (int k = 0; k < TPG; ++k)
#pragma unroll
    for (int j = 0; j < 4; ++j)
      q[k][j] = p[k * (TILE / 4) + j * THREADS + t];

  // same reduction tree per tile as the 8192-block version (bit-identical part[])
  float s[TPG];
#pragma unroll
  for (int k = 0; k < TPG; ++k) {
    float a = (q[k][0].x + q[k][0].y) + (q[k][0].z + q[k][0].w);
    float b = (q[k][1].x + q[k][1].y) + (q[k][1].z + q[k][1].w);
    float c = (q[k][2].x + q[k][2].y) + (q[k][2].z + q[k][2].w);
    float d = (q[k][3].x + q[k][3].y) + (q[k][3].z + q[k][3].w);
    s[k] = (a + b) + (c + d);
  }
#pragma unroll
  for (int k = 0; k < TPG; ++k)
#pragma unroll
    for (int o = 32; o > 0; o >>= 1) s[k] += __shfl_down(s[k], o, 64);

  __shared__ float wsum[4][TPG];
  if (lane == 0)
#pragma unroll
    for (int k = 0; k < TPG; ++k) wsum[wid][k] = s[k];
  __syncthreads();
  if (t < TPG)
    part[blk * TPG + t] =
        (wsum[0][t] + wsum[1][t]) + (wsum[2][t] + wsum[3][t]);
}

// ---------------- B: offset + scan + write, 4 tiles/block ----------------
__global__ __launch_bounds__(THREADS) void integ_scan(
    const float* __restrict__ x, float* __restrict__ y,
    const float* __restrict__ part) {
  const int blk  = blockIdx.x;
  const int row  = blk >> 6;               // / GROUPS_PER_ROW
  const int g    = blk & (GROUPS_PER_ROW - 1);
  const int tb0  = g * TPG;                // first tile index within row
  const int t    = threadIdx.x;
  const int lane = t & 63;
  const int wid  = t >> 6;

  __shared__ float s_pred[4];
  __shared__ float s_wscan[2][4];          // double-buffered on tile parity

  // predecessor tile-sums: once per block (amortized over 4 tiles)
  float ps = (t < tb0) ? part[(row << 8) + t] : 0.f;
#pragma unroll
  for (int o = 32; o > 0; o >>= 1) ps += __shfl_xor(ps, o, 64);
  if (lane == 0) s_pred[wid] = ps;

  const float4* p = (const float4*)(x + (size_t)blk * (TILE * TPG));

  // prefetch tile 0 (16 contiguous floats per thread)
  float4 cur[4];
#pragma unroll
  for (int j = 0; j < 4; ++j) cur[j] = p[4 * t + j];

  float carry = 0.f;
#pragma unroll
  for (int k = 0; k < TPG; ++k) {
    // prefetch next tile while scanning this one
    float4 nxt[4];
    if (k < TPG - 1) {
#pragma unroll
      for (int j = 0; j < 4; ++j)
        nxt[j] = p[(k + 1) * (TILE / 4) + 4 * t + j];
    }

    float v[PER_THREAD];
#pragma unroll
    for (int j = 0; j < 4; ++j) {
      v[4 * j + 0] = cur[j].x; v[4 * j + 1] = cur[j].y;
      v[4 * j + 2] = cur[j].z; v[4 * j + 3] = cur[j].w;
    }

    // thread-local inclusive scan
#pragma unroll
    for (int i = 1; i < PER_THREAD; ++i) v[i] += v[i - 1];
    const float tsum = v[PER_THREAD - 1];

    // wave scan of per-thread sums
    float s = tsum;
#pragma unroll
    for (int d = 1; d < 64; d <<= 1) {
      float n = __shfl_up(s, d, 64);
      if (lane >= d) s += n;
    }
    if (lane == 63) s_wscan[k & 1][wid] = s;
    __syncthreads();   // covers s_pred (k==0) and s_wscan[k&1]

    if (k == 0)
      carry = (s_pred[0] + s_pred[1]) + (s_pred[2] + s_pred[3]);

    float off = carry + (s - tsum);
#pragma unroll
    for (int w = 0; w < 4; ++w) off += (w < wid) ? s_wscan[k & 1][w] : 0.f;
    const float blockTotal = (s_wscan[k & 1][0] + s_wscan[k & 1][1]) +
                             (s_wscan[k & 1][2] + s_wscan[k & 1][3]);

#pragma unroll
    for (int i = 0; i < PER_THREAD; ++i) v[i] += off;

    float4* qo = (float4*)((float*)(y + (size_t)blk * (TILE * TPG)) +
                           k * TILE + 16 * t);
#pragma unroll
    for (int j = 0; j < 4; ++j) {
      float4 o;
      o.x = v[4 * j + 0]; o.y = v[4 * j + 1];
      o.z = v[4 * j + 2]; o.w = v[4 * j + 3];
      qo[j] = o;
    }

    carry += blockTotal;
#pragma unroll
    for (int j = 0; j < 4; ++j) cur[j] = nxt[j];
    // no second barrier: next write targets s_wscan[(k+1)&1]; slot k&1 is
    // rewritten only at k+2, after the k+1 barrier has retired all readers
  }
}

extern "C" void kernel_launch(void* const* d_in, const int* in_sizes, int n_in,
                              void* d_out, int out_size, void* d_ws, size_t ws_size,
                              hipStream_t stream) {
  const float* x = (const float*)d_in[0];
  float* y = (float*)d_out;
  float* part = (float*)d_ws;   // 8192 floats = 32 KB

  integ_reduce<<<TOTAL_GROUPS, THREADS, 0, stream>>>(x, part);
  integ_scan  <<<TOTAL_GROUPS, THREADS, 0, stream>>>(x, y, part);
}

// Round 8
// 252.397 us; speedup vs baseline: 1.0342x; 1.0342x over previous
//
#include <hip/hip_runtime.h>

// Integrator: y = cumsum(x, axis=-1) over (8,4,1048576) fp32.
// Two-kernel reduce-then-scan — the measured-optimal structure (252.3us).
// Ledger: decoupled lookback +955us (cross-block spin on 8-XCD coherence
// fabric); cooperative grid.sync +120us; nt-stores +130us (bypass L2
// write-combining -> 2.5x WRITE_SIZE); 8192-float tiles +6us; 4-tiles/block
// ILP/prefetch +9us. Block-count curve: 2048->261, 4096->258, 8192->252 (min).
//   A: per-tile sums (read x once, coalesced float4, independent accumulators)
//   B: wave-parallel reduce of <=255 predecessor tile sums (part[] 32 KB,
//      L2-hot), 16-elem/thread local scan, wave+block scan, add offset,
//      plain cached float4 stores (L2 write-combines to full lines).
// HBM floor: 134 MB read + 134 MB write; B's x re-read is L3-resident.

constexpr int ROWS           = 32;        // B*C = 8*4
constexpr int T_LEN          = 1048576;
constexpr int THREADS        = 256;
constexpr int PER_THREAD     = 16;        // contiguous floats per thread in B
constexpr int TILE           = THREADS * PER_THREAD;   // 4096
constexpr int BLOCKS_PER_ROW = T_LEN / TILE;           // 256
constexpr int TOTAL_BLOCKS   = ROWS * BLOCKS_PER_ROW;  // 8192

// ---------------- A: per-tile sums ----------------
__global__ __launch_bounds__(THREADS) void integ_reduce(
    const float* __restrict__ x, float* __restrict__ part) {
  const int blk = blockIdx.x;
  const size_t base = (size_t)blk * TILE;
  const float4* p = (const float4*)(x + base);
  const int t = threadIdx.x;
  const int lane = t & 63;
  const int wid  = t >> 6;

  // 4 dense float4 sweeps, independent accumulators (no serial FMA chain)
  float4 a = p[0 * THREADS + t];
  float4 b = p[1 * THREADS + t];
  float4 c = p[2 * THREADS + t];
  float4 d = p[3 * THREADS + t];
  float s0 = (a.x + a.y) + (a.z + a.w);
  float s1 = (b.x + b.y) + (b.z + b.w);
  float s2 = (c.x + c.y) + (c.z + c.w);
  float s3 = (d.x + d.y) + (d.z + d.w);
  float s = (s0 + s1) + (s2 + s3);
#pragma unroll
  for (int o = 32; o > 0; o >>= 1) s += __shfl_down(s, o, 64);

  __shared__ float wsum[4];
  if (lane == 0) wsum[wid] = s;
  __syncthreads();
  if (t == 0) part[blk] = (wsum[0] + wsum[1]) + (wsum[2] + wsum[3]);
}

// ---------------- B: offset + local scan + write ----------------
__global__ __launch_bounds__(THREADS) void integ_scan(
    const float* __restrict__ x, float* __restrict__ y,
    const float* __restrict__ part) {
  const int blk = blockIdx.x;
  const int row = blk >> 8;                // / BLOCKS_PER_ROW
  const int tb  = blk & (BLOCKS_PER_ROW - 1);
  const int t = threadIdx.x;
  const int lane = t & 63;
  const int wid  = t >> 6;

  __shared__ float s_pred[4];    // per-wave predecessor partial sums
  __shared__ float s_wscan[4];   // per-wave scan totals

  // 1) predecessor tile-sum: thread t owns part[row*256 + t] if t < tb
  float ps = (t < tb) ? part[(row << 8) + t] : 0.f;
#pragma unroll
  for (int o = 32; o > 0; o >>= 1) ps += __shfl_xor(ps, o, 64);
  if (lane == 0) s_pred[wid] = ps;

  // 2) load tile: 16 contiguous floats per thread (issues early, long latency)
  const size_t base = (size_t)blk * TILE + (size_t)t * PER_THREAD;
  const float4* p = (const float4*)(x + base);
  float v[PER_THREAD];
#pragma unroll
  for (int j = 0; j < PER_THREAD / 4; ++j) {
    float4 q = p[j];
    v[4 * j + 0] = q.x; v[4 * j + 1] = q.y; v[4 * j + 2] = q.z; v[4 * j + 3] = q.w;
  }

  // 3) thread-local inclusive scan
#pragma unroll
  for (int i = 1; i < PER_THREAD; ++i) v[i] += v[i - 1];
  const float tsum = v[PER_THREAD - 1];

  // 4) block scan of per-thread sums
  float s = tsum;
#pragma unroll
  for (int d = 1; d < 64; d <<= 1) {
    float n = __shfl_up(s, d, 64);
    if (lane >= d) s += n;
  }
  if (lane == 63) s_wscan[wid] = s;
  __syncthreads();   // single barrier: covers s_pred and s_wscan

  float off = (s_pred[0] + s_pred[1]) + (s_pred[2] + s_pred[3]);
  float prev = 0.f;
#pragma unroll
  for (int w = 0; w < 4; ++w) prev += (w < wid) ? s_wscan[w] : 0.f;
  off += prev + s - tsum;        // + exclusive prefix within tile

#pragma unroll
  for (int i = 0; i < PER_THREAD; ++i) v[i] += off;

  // 5) plain cached stores — L2 write-combines adjacent lanes into full lines
  float4* q = (float4*)(y + base);
#pragma unroll
  for (int j = 0; j < PER_THREAD / 4; ++j) {
    float4 o;
    o.x = v[4 * j + 0]; o.y = v[4 * j + 1];
    o.z = v[4 * j + 2]; o.w = v[4 * j + 3];
    q[j] = o;
  }
}

extern "C" void kernel_launch(void* const* d_in, const int* in_sizes, int n_in,
                              void* d_out, int out_size, void* d_ws, size_t ws_size,
                              hipStream_t stream) {
  const float* x = (const float*)d_in[0];
  float* y = (float*)d_out;
  float* part = (float*)d_ws;   // TOTAL_BLOCKS floats = 32 KB

  integ_reduce<<<TOTAL_BLOCKS, THREADS, 0, stream>>>(x, part);
  integ_scan  <<<TOTAL_BLOCKS, THREADS, 0, stream>>>(x, y, part);
}